// Round 1
// baseline (306.512 us; speedup 1.0000x reference)
//
#include <hip/hip_runtime.h>

// LeakyZOPlainOnce: 32-step LIF scan with LocalZO straight-through surrogate.
// inputs:  d_in[0] = x  (T*B*F fp32), d_in[1] = z (same shape)
// output:  d_out    = spikes (T*B*F fp32)
//
// Determinism note: spike = (h - surr*v) + surr*v is NOT exactly h when
// surr*v > 2 (residual ~1e-6 feeds the u recurrence). With 33.5M threshold
// decisions, some v land within 1e-7 of 0, so we must replicate the numpy
// fp32 op order EXACTLY: separate mul+add (no FMA contraction), true IEEE
// division by 0.1f, strict comparisons.

constexpr int BATCH = 128;
constexpr int FDIM  = 8192;
constexpr int STEP  = BATCH * FDIM;   // elements per time step = 1,048,576
constexpr int VEC   = 4;              // float4 per thread

__global__ __launch_bounds__(256) void lif_zo_kernel(
    const float* __restrict__ x,
    const float* __restrict__ z,
    float* __restrict__ out,
    int T)
{
#pragma clang fp contract(off)
    const int tid = blockIdx.x * blockDim.x + threadIdx.x;
    long idx = (long)tid * VEC;

    float u[VEC];
#pragma unroll
    for (int c = 0; c < VEC; ++c) u[c] = 0.0f;

    for (int t = 0; t < T; ++t, idx += STEP) {
        const float4 xt = *reinterpret_cast<const float4*>(x + idx);
        const float4 zt = *reinterpret_cast<const float4*>(z + idx);
        const float xs[VEC] = {xt.x, xt.y, xt.z, xt.w};
        const float zs[VEC] = {zt.x, zt.y, zt.z, zt.w};
        float ss[VEC];
#pragma unroll
        for (int c = 0; c < VEC; ++c) {
            // u = beta*u + x   (separate mul + add, matches numpy)
            float uu = 0.5f * u[c];
            uu = uu + xs[c];
            // v = u - u_th
            float v = uu - 1.0f;
            // surr = (|z| / (2*delta)) * (|v| < delta*|z|)
            float az   = fabsf(zs[c]);
            float thr  = 0.05f * az;
            float ind  = (fabsf(v) < thr) ? 1.0f : 0.0f;
            float surr = (az / 0.1f) * ind;
            // h = (v > 0)
            float h = (v > 0.0f) ? 1.0f : 0.0f;
            // spike = (h - surr*v) + surr*v   (straight-through forward)
            float a     = surr * v;
            float spike = (h - a) + a;
            // u = u - spike * u_th
            u[c] = uu - spike * 1.0f;
            ss[c] = spike;
        }
        const float4 s4 = make_float4(ss[0], ss[1], ss[2], ss[3]);
        *reinterpret_cast<float4*>(out + idx) = s4;
    }
}

extern "C" void kernel_launch(void* const* d_in, const int* in_sizes, int n_in,
                              void* d_out, int out_size, void* d_ws, size_t ws_size,
                              hipStream_t stream)
{
    const float* x = (const float*)d_in[0];
    const float* z = (const float*)d_in[1];
    float* out = (float*)d_out;

    const int total = in_sizes[0];          // T * B * F
    const int T = total / STEP;             // = 32 for this problem

    const int nthreads = STEP / VEC;        // 262,144
    const int block = 256;
    const int grid = nthreads / block;      // 1024

    lif_zo_kernel<<<grid, block, 0, stream>>>(x, z, out, T);
}